// Round 13
// baseline (55.869 us; speedup 1.0000x reference)
//
#include <hip/hip_runtime.h>

// APLoss (r2d2 QAPLoss). B=2, H=W=32 -> N=M=1024/batch, D=128, 25 bins.
// u = 24*(1-sim); cumsum_k of triangular bins = clamp(k+1-u, 0, 1).
// R13: decoupled pipeline to kill cross-XCD dbt re-reads (128 MB -> 24 MB):
//   k_gs   : grid-sample desc2 -> dbt[b][c][m]            (256 blk)
//   k_gemm : 64q x 64m tiled sim GEMM -> simm[bq][m]      (512 blk, 0 LDS)
//   k_hist : R10's hist+AP per 8q x all-m, sim from global (256 blk)
//   k_sum  : 256 partials -> out                           (1 blk)

#define NQB 25

// DPP butterfly add over 16-lane rows (pure VALU, no LDS pipe).
template<int CTRL>
__device__ __forceinline__ float dppadd(float v) {
    int s = __builtin_amdgcn_update_dpp(0, __float_as_int(v), CTRL, 0xf, 0xf, true);
    return v + __int_as_float(s);
}
__device__ __forceinline__ float red16(float v) {
    v = dppadd<0xB1>(v);   // quad_perm xor1
    v = dppadd<0x4E>(v);   // quad_perm xor2
    v = dppadd<0x141>(v);  // row_half_mirror = xor7
    v = dppadd<0x140>(v);  // row_mirror      = xor15
    return v;              // every lane: its 16-lane-row sum
}

// ---- K1: bilinear grid-sample desc2 -> dbt[b][c][m]; block = (b,c) ---------
__global__ __launch_bounds__(256) void k_gs(const float* __restrict__ desc2,
                                            const float* __restrict__ grd,
                                            float* __restrict__ dbt)
{
    __shared__ float plane[1024];
    int r = blockIdx.x;            // b*128 + c
    int b = r >> 7;
    int tid = threadIdx.x;
    const float* src = desc2 + ((size_t)r << 10);
    *(float4*)&plane[tid * 4] = *(const float4*)&src[tid * 4];
    __syncthreads();
#pragma unroll
    for (int e = 0; e < 4; e++) {
        int m = tid + (e << 8);
        int pos = (b << 10) + m;
        float2 g = ((const float2*)grd)[pos];
        float fx = ((g.x + 1.f) * 32.f - 1.f) * 0.5f;
        float fy = ((g.y + 1.f) * 32.f - 1.f) * 0.5f;
        float x0f = floorf(fx), y0f = floorf(fy);
        float wx1 = fx - x0f, wy1 = fy - y0f;
        float wx0 = 1.f - wx1, wy0 = 1.f - wy1;
        int x0 = (int)x0f, y0 = (int)y0f;
        float acc = 0.f;
        if ((unsigned)y0 < 32u && (unsigned)x0 < 32u)
            acc += wy0 * wx0 * plane[(y0 << 5) + x0];
        if ((unsigned)y0 < 32u && (unsigned)(x0 + 1) < 32u)
            acc += wy0 * wx1 * plane[(y0 << 5) + x0 + 1];
        if ((unsigned)(y0 + 1) < 32u && (unsigned)x0 < 32u)
            acc += wy1 * wx0 * plane[((y0 + 1) << 5) + x0];
        if ((unsigned)(y0 + 1) < 32u && (unsigned)(x0 + 1) < 32u)
            acc += wy1 * wx1 * plane[((y0 + 1) << 5) + x0 + 1];
        dbt[((size_t)r << 10) + m] = acc;
    }
}

// ---- K2: sim GEMM, 64q x 64m tile; 512 blocks x 256 thr, no LDS ------------
// Wave ty handles 16 consecutive q (wave-uniform scalar loads); lane = m.
// Same c-order fmaf chain as R10 -> bitwise-identical sims.
__global__ __launch_bounds__(256) void k_gemm(const float* __restrict__ desc1,
                                              const float* __restrict__ dbt,
                                              float* __restrict__ simm)
{
    int bid = blockIdx.x;          // b*256 + qt*16 + mt
    int b = bid >> 8;
    int r = bid & 255;
    int qt = r >> 4, mt = r & 15;
    int tid = threadIdx.x;
    int ty = tid >> 6, lane = tid & 63;

    const float* d1 = desc1 + ((size_t)b << 17) + qt * 64 + ty * 16; // + (c<<10)+j
    const float* dp = dbt + ((size_t)b << 17) + mt * 64 + lane;      // + (c<<10)

    float acc[16];
#pragma unroll
    for (int j = 0; j < 16; j++) acc[j] = 0.f;

    float dA[8], dB[8];
#define LOADC(buf, ch) { int cb = (ch) << 3;                                   \
    _Pragma("unroll")                                                          \
    for (int i = 0; i < 8; i++) buf[i] = dp[(size_t)(cb + i) << 10]; }
#define FMAC(ch, buf) { int cb = (ch) << 3;                                    \
    _Pragma("unroll")                                                          \
    for (int i = 0; i < 8; i++) {                                              \
        const float* qp = d1 + ((size_t)(cb + i) << 10);                       \
        _Pragma("unroll")                                                      \
        for (int j = 0; j < 16; j++) acc[j] = fmaf(qp[j], buf[i], acc[j]); } }

    LOADC(dA, 0);
    for (int ch = 0; ch < 16; ch += 2) {
        LOADC(dB, ch + 1);              // issue next chunk
        FMAC(ch, dA);                   // consume current
        if (ch + 2 < 16) LOADC(dA, ch + 2);
        FMAC(ch + 1, dB);
    }
#undef LOADC
#undef FMAC

    float* sp = simm + ((((size_t)(b << 10)) + qt * 64 + ty * 16) << 10)
              + mt * 64 + lane;
#pragma unroll
    for (int j = 0; j < 16; j++) sp[(size_t)j << 10] = acc[j];
}

// ---- K3: histogram + AP; block = 8 q x ALL 1024 m, 512 thr (8 waves) -------
// Wave = query; lane l owns m = l + 64e. Sim + labels batched upfront (32
// loads in flight). Hist/red16/AP verbatim from R10.
__global__ __launch_bounds__(512) void k_hist(const float* __restrict__ simm,
                                              const int* __restrict__ label,
                                              float* __restrict__ appart)
{
    __shared__ float CNs[8][4][NQB];
    __shared__ float CRs[8][4][NQB];
    __shared__ float apb[8];

    int tid = threadIdx.x;
    int qg0 = blockIdx.x << 3;
    int q = tid >> 6, l = tid & 63;
    int qg = qg0 + q;

    const int* lp = label + ((size_t)qg << 10) + l;
    const float* sp = simm + ((size_t)qg << 10) + l;

    int lv[16];
    float sv[16];
#pragma unroll
    for (int e = 0; e < 16; e++) lv[e] = lp[(size_t)(e << 6)];
#pragma unroll
    for (int e = 0; e < 16; e++) sv[e] = sp[(size_t)(e << 6)];

    float CN[NQB], CR[NQB];
#pragma unroll
    for (int k = 0; k < NQB; k++) { CN[k] = 0.f; CR[k] = 0.f; }
#pragma unroll
    for (int e = 0; e < 16; e++) {
        float u = fmaf(-24.f, sv[e], 24.f);
        float lfv = (float)lv[e];
#pragma unroll
        for (int k = 0; k < NQB; k++) {
            float t = fminf(fmaxf((float)(k + 1) - u, 0.f), 1.f);  // v_med3
            CN[k] += t;
            CR[k] = fmaf(lfv, t, CR[k]);
        }
    }
#pragma unroll
    for (int k = 0; k < NQB; k++) { CN[k] = red16(CN[k]); CR[k] = red16(CR[k]); }
    if ((l & 15) == 0) {
        int rec = l >> 4;
#pragma unroll
        for (int k = 0; k < NQB; k++) { CNs[q][rec][k] = CN[k]; CRs[q][rec][k] = CR[k]; }
    }
    __syncthreads();

    if (tid < 8) {
        float ap = 0.f, prev = 0.f;
#pragma unroll
        for (int k = 0; k < NQB; k++) {
            float cn = CNs[tid][0][k] + CNs[tid][1][k] + CNs[tid][2][k] + CNs[tid][3][k];
            float cr = CRs[tid][0][k] + CRs[tid][1][k] + CRs[tid][2][k] + CRs[tid][3][k];
            float pr = cr / (1e-16f + cn);
            ap += pr * (cr - prev);
            prev = cr;
        }
        apb[tid] = ap / prev;
    }
    __syncthreads();
    if (tid == 0) {
        float v = 0.f;
#pragma unroll
        for (int q2 = 0; q2 < 8; q2++) v += apb[q2];
        appart[blockIdx.x] = v;
    }
}

// ---- K4: final reduce of per-block sums -> d_out ---------------------------
__global__ __launch_bounds__(256) void k_sum(const float* __restrict__ appart,
                                             float* __restrict__ out,
                                             int nb, float invn)
{
    int tid = threadIdx.x;
    float v = 0.f;
    for (int i = tid; i < nb; i += 256) v += appart[i];
    for (int off = 32; off; off >>= 1) v += __shfl_xor(v, off, 64);
    __shared__ float wsum[4];
    if ((tid & 63) == 0) wsum[tid >> 6] = v;
    __syncthreads();
    if (tid == 0) out[0] = (wsum[0] + wsum[1] + wsum[2] + wsum[3]) * invn;
}

extern "C" void kernel_launch(void* const* d_in, const int* in_sizes, int n_in,
                              void* d_out, int out_size, void* d_ws, size_t ws_size,
                              hipStream_t stream)
{
    const float* desc1 = (const float*)d_in[0];
    const float* desc2 = (const float*)d_in[1];
    // d_in[2] = reliability: unused by the reference output
    const float* grd   = (const float*)d_in[3];
    const int*   label = (const int*)d_in[4];

    int B = in_sizes[0] / (128 * 1024);
    int npos = B * 1024;

    float* ws = (float*)d_ws;
    float* dbt    = ws;                            // npos*128  ([b][c][m])
    float* simm   = dbt + (size_t)npos * 128;      // npos*1024 ([bq][m])
    float* appart = simm + (size_t)npos * 1024;    // npos/8
    float* out = (float*)d_out;

    k_gs<<<B * 128, 256, 0, stream>>>(desc2, grd, dbt);
    k_gemm<<<B * 256, 256, 0, stream>>>(desc1, dbt, simm);
    k_hist<<<npos / 8, 512, 0, stream>>>(simm, label, appart);
    k_sum<<<1, 256, 0, stream>>>(appart, out, npos / 8, 1.f / (float)npos);
}

// Round 14
// 25.555 us; speedup vs baseline: 2.1862x; 2.1862x over previous
//
#include <hip/hip_runtime.h>

// APLoss (r2d2 QAPLoss). B=2, H=W=32 -> N=M=1024/batch, D=128, 25 bins.
// u = 24*(1-sim); cumsum_k of triangular bins = clamp(k+1-u, 0, 1).
// R14: grid-sample COMMUTES with the GEMM (bilinear warp is linear over
// channels): sim[n][m] = sum_tap w_tap(m) * S0[n][p_tap(m)], S0 = d1^T d2.
// -> 2 launches only:
//   k_main : S0 tile (8q x 1024p, R10's ping-pong GEMM on desc2 directly)
//            -> on-the-fly bilinear warp + histogram + AP  (256 blk x 512 thr)
//   k_final: 256 partials -> out.

#define NQB 25

// DPP butterfly add over 16-lane rows (pure VALU, no LDS pipe).
template<int CTRL>
__device__ __forceinline__ float dppadd(float v) {
    int s = __builtin_amdgcn_update_dpp(0, __float_as_int(v), CTRL, 0xf, 0xf, true);
    return v + __int_as_float(s);
}
__device__ __forceinline__ float red16(float v) {
    v = dppadd<0xB1>(v);   // quad_perm xor1
    v = dppadd<0x4E>(v);   // quad_perm xor2
    v = dppadd<0x141>(v);  // row_half_mirror = xor7
    v = dppadd<0x140>(v);  // row_mirror      = xor15
    return v;              // every lane: its 16-lane-row sum
}

// ---- sim helpers: chunk = 8 consecutive c (verbatim R10, src = desc2) ------
__device__ __forceinline__ void loadc(const float* __restrict__ dp, int ch,
                                      float* d)
{
    int cb = ch << 3;
#pragma unroll
    for (int i = 0; i < 8; i++) {
        d[i]     = dp[(size_t)(cb + i) << 10];           // p = tid
        d[8 + i] = dp[(((size_t)(cb + i)) << 10) + 512]; // p = tid + 512
    }
}
__device__ __forceinline__ void fmac(const float* __restrict__ d1, int ch,
                                     const float* d, float* a0, float* a1)
{
    int cb = ch << 3;
#pragma unroll
    for (int i = 0; i < 8; i++) {
        const float* qp = d1 + ((size_t)(cb + i) << 10);
#pragma unroll
        for (int qq = 0; qq < 8; qq++) {
            float qv = qp[qq];   // wave-uniform -> scalar load
            a0[qq] = fmaf(qv, d[i], a0[qq]);
            a1[qq] = fmaf(qv, d[8 + i], a1[qq]);
        }
    }
}

// ---- K1: fused S0 GEMM + warp + histogram + AP; 8 q x all m, 512 thr -------
__global__ __launch_bounds__(512) void k_main(const float* __restrict__ desc1,
                                              const float* __restrict__ desc2,
                                              const float* __restrict__ grd,
                                              const int* __restrict__ label,
                                              float* __restrict__ appart)
{
    __shared__ float s[8][1024];    // S0 tile: 8 queries x 1024 grid positions
    __shared__ float CNs[8][4][NQB];
    __shared__ float CRs[8][4][NQB];
    __shared__ float apb[8];

    int tid = threadIdx.x;
    int qg0 = blockIdx.x << 3;      // global query base (b*1024 + n0)
    int b = qg0 >> 10;
    int n0 = qg0 & 1023;

    // ---- prefetch labels + grid coords for my 16 m's (hide under GEMM) ----
    int q = tid >> 6, l = tid & 63; // hist roles: wave = query, lane = l
    const int* lp = label + ((size_t)(qg0 + q) << 10) + l;
    int lv[16];
#pragma unroll
    for (int e = 0; e < 16; e++) lv[e] = lp[(size_t)(e << 6)];
    const float2* gp = (const float2*)grd + ((size_t)b << 10) + l;
    float2 gv[16];
#pragma unroll
    for (int e = 0; e < 16; e++) gv[e] = gp[(size_t)(e << 6)];

    // ---- S0 GEMM phase: 2-deep ping-pong over 16 chunks of 8 c ----
    const float* d1 = desc1 + ((size_t)b << 17) + n0;  // q-row: d1[(c<<10)+qq]
    const float* dp = desc2 + ((size_t)b << 17) + tid; // p-col: dp[c<<10]

    float a0[8], a1[8];
#pragma unroll
    for (int qq = 0; qq < 8; qq++) { a0[qq] = 0.f; a1[qq] = 0.f; }

    float dA[16], dB[16];
    loadc(dp, 0, dA);
    for (int ch = 0; ch < 16; ch += 2) {
        loadc(dp, ch + 1, dB);          // issue next chunk
        fmac(d1, ch, dA, a0, a1);       // consume current
        if (ch + 2 < 16) loadc(dp, ch + 2, dA);
        fmac(d1, ch + 1, dB, a0, a1);
    }
#pragma unroll
    for (int qq = 0; qq < 8; qq++) { s[qq][tid] = a0[qq]; s[qq][tid + 512] = a1[qq]; }
    __syncthreads();

    // ---- histogram with on-the-fly bilinear warp of the S0 row ----
    float CN[NQB], CR[NQB];
#pragma unroll
    for (int k = 0; k < NQB; k++) { CN[k] = 0.f; CR[k] = 0.f; }
    const float* sq = s[q];
#pragma unroll
    for (int e = 0; e < 16; e++) {
        float gx = gv[e].x, gy = gv[e].y;
        float fx = ((gx + 1.f) * 32.f - 1.f) * 0.5f;
        float fy = ((gy + 1.f) * 32.f - 1.f) * 0.5f;
        float x0f = floorf(fx), y0f = floorf(fy);
        float wx1 = fx - x0f, wy1 = fy - y0f;
        float wx0 = 1.f - wx1, wy0 = 1.f - wy1;
        int x0 = (int)x0f, y0 = (int)y0f;
        int x1 = x0 + 1, y1 = y0 + 1;
        bool bx0 = (unsigned)x0 < 32u, bx1 = (unsigned)x1 < 32u;
        bool by0 = (unsigned)y0 < 32u, by1 = (unsigned)y1 < 32u;
        float w00 = (by0 && bx0) ? wy0 * wx0 : 0.f;
        float w01 = (by0 && bx1) ? wy0 * wx1 : 0.f;
        float w10 = (by1 && bx0) ? wy1 * wx0 : 0.f;
        float w11 = (by1 && bx1) ? wy1 * wx1 : 0.f;
        int xc0 = min(max(x0, 0), 31), xc1 = min(max(x1, 0), 31);
        int yc0 = min(max(y0, 0), 31), yc1 = min(max(y1, 0), 31);
        float sv = w00 * sq[(yc0 << 5) + xc0];
        sv = fmaf(w01, sq[(yc0 << 5) + xc1], sv);
        sv = fmaf(w10, sq[(yc1 << 5) + xc0], sv);
        sv = fmaf(w11, sq[(yc1 << 5) + xc1], sv);

        float u = fmaf(-24.f, sv, 24.f);
        float lfv = (float)lv[e];
#pragma unroll
        for (int k = 0; k < NQB; k++) {
            float t = fminf(fmaxf((float)(k + 1) - u, 0.f), 1.f);  // v_med3
            CN[k] += t;
            CR[k] = fmaf(lfv, t, CR[k]);
        }
    }
#pragma unroll
    for (int k = 0; k < NQB; k++) { CN[k] = red16(CN[k]); CR[k] = red16(CR[k]); }
    if ((l & 15) == 0) {
        int rec = l >> 4;
#pragma unroll
        for (int k = 0; k < NQB; k++) { CNs[q][rec][k] = CN[k]; CRs[q][rec][k] = CR[k]; }
    }
    __syncthreads();

    // ---- AP per query (8 threads), block sum -> 1 float ----
    if (tid < 8) {
        float ap = 0.f, prev = 0.f;
#pragma unroll
        for (int k = 0; k < NQB; k++) {
            float cn = CNs[tid][0][k] + CNs[tid][1][k] + CNs[tid][2][k] + CNs[tid][3][k];
            float cr = CRs[tid][0][k] + CRs[tid][1][k] + CRs[tid][2][k] + CRs[tid][3][k];
            float pr = cr / (1e-16f + cn);
            ap += pr * (cr - prev);
            prev = cr;
        }
        apb[tid] = ap / prev;
    }
    __syncthreads();
    if (tid == 0) {
        float v = 0.f;
#pragma unroll
        for (int q2 = 0; q2 < 8; q2++) v += apb[q2];
        appart[blockIdx.x] = v;
    }
}

// ---- K2: final reduce of per-block sums -> d_out ---------------------------
__global__ __launch_bounds__(256) void k_final(const float* __restrict__ appart,
                                               float* __restrict__ out,
                                               int nb, float invn)
{
    int tid = threadIdx.x;
    float v = 0.f;
    for (int i = tid; i < nb; i += 256) v += appart[i];
    for (int off = 32; off; off >>= 1) v += __shfl_xor(v, off, 64);
    __shared__ float wsum[4];
    if ((tid & 63) == 0) wsum[tid >> 6] = v;
    __syncthreads();
    if (tid == 0) out[0] = (wsum[0] + wsum[1] + wsum[2] + wsum[3]) * invn;
}

extern "C" void kernel_launch(void* const* d_in, const int* in_sizes, int n_in,
                              void* d_out, int out_size, void* d_ws, size_t ws_size,
                              hipStream_t stream)
{
    const float* desc1 = (const float*)d_in[0];
    const float* desc2 = (const float*)d_in[1];
    // d_in[2] = reliability: unused by the reference output
    const float* grd   = (const float*)d_in[3];
    const int*   label = (const int*)d_in[4];

    int B = in_sizes[0] / (128 * 1024);
    int npos = B * 1024;
    int nblk = npos / 8;

    float* ws = (float*)d_ws;
    float* appart = ws;                 // nblk floats
    float* out = (float*)d_out;

    k_main<<<nblk, 512, 0, stream>>>(desc1, desc2, grd, label, appart);
    k_final<<<1, 256, 0, stream>>>(appart, out, nblk, 1.f / (float)npos);
}